// Round 12
// baseline (136.992 us; speedup 1.0000x reference)
//
#include <hip/hip_runtime.h>
#include <math.h>

// B=4, T=2048, N_EMBD=1024, HEAD=64.
// Reference multiplies scores by sqrt(64)=8; we fold 8*log2(e) into q and use exp2.
#define NE 1024
#define HS 64
#define TT 2048
#define QSC 11.541560327111707f   // 8 * log2(e)

typedef __bf16    v8bf __attribute__((ext_vector_type(8)));
typedef _Float16  v8h  __attribute__((ext_vector_type(8)));
typedef float     v4f  __attribute__((ext_vector_type(4)));

#define MFMA_BF(a, b, c)  __builtin_amdgcn_mfma_f32_16x16x32_bf16((a), (b), (c), 0, 0, 0)
#define MFMA_F16(a, b, c) __builtin_amdgcn_mfma_f32_16x16x32_f16((a), (b), (c), 0, 0, 0)

// async global->LDS DMA (lands at wave-uniform base + lane*size)
__device__ __forceinline__ void gl_lds16(const void* g, void* l) {
    __builtin_amdgcn_global_load_lds(
        (const __attribute__((address_space(1))) unsigned int*)g,
        (__attribute__((address_space(3))) unsigned int*)l, 16, 0, 0);
}

// raw barrier with manual waitcnt: NO compiler-inserted vmcnt(0) drain.
// imm encoding (gfx9): vmcnt[3:0] | exp[6:4] | lgkm[11:8] | vmcnt[5:4]@[15:14]
#define SYNC_VM(imm) do {                                   \
    __asm__ __volatile__("" ::: "memory");                  \
    __builtin_amdgcn_s_waitcnt(imm);                        \
    __builtin_amdgcn_s_barrier();                           \
    __asm__ __volatile__("" ::: "memory");                  \
} while (0)
#define WAIT_VM5  0x0075   // vmcnt(5) + lgkmcnt(0): newest stage stays in flight
#define WAIT_VM0  0x0070   // vmcnt(0) + lgkmcnt(0)

// ---------------------------------------------------------------------------
// prep_w: build the W "image" — hi/lo bf16, pre-arranged so that a linear
// global_load_lds stream lands B-fragments in LDS with an XOR-16B swizzle.
// Image layout (bytes): [step 0..31][ct 0..11][plane hi/lo][c 0..15][p16 0..3][16B]
//   content of (step,ct,pl,c,p16) = W[k = step*32 + (p16^(c&3))*8 + j][n = ct*16+c]
// ---------------------------------------------------------------------------
__global__ __launch_bounds__(256) void prep_w(
    const float* __restrict__ Wq, const float* __restrict__ Wk,
    const float* __restrict__ Wv, char* __restrict__ imgW)
{
    __shared__ float t[64][65];
    const int bx = blockIdx.x, by = blockIdx.y;
    const float* W = (by == 0) ? Wq : ((by == 1) ? Wk : Wv);
    const int tid = threadIdx.x;
    const int cc = tid & 63, r4 = tid >> 6;
    #pragma unroll
    for (int p = 0; p < 16; ++p) {
        const int k = p * 4 + r4;
        t[k][cc] = W[(size_t)(bx * 64 + k) * HS + cc];   // coalesced
    }
    __syncthreads();
    #pragma unroll
    for (int e = 0; e < 4; ++e) {
        const int chunk = tid + e * 256;
        const int s2   = chunk >> 9;
        const int rem  = chunk & 511;
        const int ctl  = rem >> 7;
        const int rem2 = rem & 127;
        const int pl   = rem2 >> 6;
        const int rem3 = rem2 & 63;
        const int c    = rem3 >> 2;
        const int p16  = rem3 & 3;
        const int kb   = s2 * 32 + ((p16 ^ (c & 3)) << 3);
        const int ncol = ctl * 16 + c;
        v8bf o;
        #pragma unroll
        for (int j = 0; j < 8; ++j) {
            const float v = t[kb + j][ncol];
            const __bf16 h = (__bf16)v;
            o[j] = pl ? (__bf16)(v - (float)h) : h;
        }
        *(v8bf*)(imgW + (size_t)(bx * 2 + s2) * 24576
                 + (by * 4 + ctl) * 2048 + pl * 1024 + c * 64 + p16 * 16) = o;
    }
}

// ---------------------------------------------------------------------------
// Projection GEMM: 256 blocks x 512 thr (1/CU), block = 64 rows x 96 cols,
// full K. 2x MAC per staged byte vs round 11: per step stage only 20 KB
// (x 8 KB + W 12 KB) for 64x96x32 MACs; aggregate W L2 traffic 393->98 MB.
// Staging by waves 0..3: exactly 5 width-16 DMAs per thread per stage ->
// vmcnt(5) waits for exactly the needed stage (newest stays in flight).
// Triple-buffered, raw barrier + manual waitcnt (no vmcnt(0) drain).
//   xbuf 8KB: [row 0..63][p32 0..3][32B], content chunk = p32 ^ (row&3)
//   wbuf 12KB: 6 cts of the W image (block's 96-col slice).
// Compute waves: (mt 0..3 = 16 rows) x (cg 0..1 = 48 cols), 9 MFMA/step.
// ---------------------------------------------------------------------------
__global__ __launch_bounds__(512, 2) void proj(
    const float* __restrict__ x, const char* __restrict__ imgW,
    const float* __restrict__ bq, const float* __restrict__ bk,
    const float* __restrict__ bv,
    __bf16* __restrict__ qh, __bf16* __restrict__ ql,
    __bf16* __restrict__ kh, __bf16* __restrict__ kl,
    _Float16* __restrict__ vt)
{
    __shared__ __align__(16) char sbuf[3][20480];   // [buf][x 8KB | W 12KB]

    const int tid = threadIdx.x, lane = tid & 63, w = tid >> 6;
    const int mt = w & 3, cg = w >> 2;               // compute mapping
    const int quad = lane >> 4, l16 = lane & 15;
    const int m0 = blockIdx.x * 64, n0 = blockIdx.y * 96;

    // staging mapping (waves 0..3 only): wave w covers x rows [w*16, w*16+16)
    // via 2 width-16 DMAs, and W bytes [w*3072, w*3072+3072) via 3 DMAs.
    const int xr0 = w * 16 + (lane >> 3);            // rows +0..7
    const int xr1 = xr0 + 8;                         // rows +8..15
    const int xs  = lane & 7;                        // 16B slot in row
    const float* gx0 = x + (size_t)(m0 + xr0) * NE
                         + (((xs >> 1) ^ (xr0 & 3)) << 3) + (xs & 1) * 4;
    const float* gx1 = x + (size_t)(m0 + xr1) * NE
                         + (((xs >> 1) ^ (xr1 & 3)) << 3) + (xs & 1) * 4;
    const char* gwb = imgW + n0 * 128 + w * 3072 + lane * 16;

    v4f acc[3];
    #pragma unroll
    for (int i = 0; i < 3; ++i) acc[i] = (v4f){0.f, 0.f, 0.f, 0.f};

    #define STAGE(ks)  do {                                               \
        if (tid < 256) {                                                  \
            char* b_ = sbuf[(ks) % 3];                                    \
            gl_lds16(gx0 + (ks) * 32, b_ + w * 2048 + lane * 16);         \
            gl_lds16(gx1 + (ks) * 32, b_ + w * 2048 + 1024 + lane * 16);  \
            const char* g_ = gwb + (size_t)(ks) * 24576;                  \
            gl_lds16(g_,        b_ + 8192 + w * 3072 + lane * 16);        \
            gl_lds16(g_ + 1024, b_ + 8192 + w * 3072 + 1024 + lane * 16); \
            gl_lds16(g_ + 2048, b_ + 8192 + w * 3072 + 2048 + lane * 16); \
        }                                                                 \
    } while (0)

    auto compute = [&](int ks) {
        const char* xb = sbuf[ks % 3];
        const char* wb = xb + 8192;
        const int rl = mt * 16 + l16;
        const int pA = quad ^ (rl & 3);
        const float4 a0 = *(const float4*)(xb + rl * 128 + pA * 32);
        const float4 a1 = *(const float4*)(xb + rl * 128 + pA * 32 + 16);
        const float av[8] = {a0.x, a0.y, a0.z, a0.w, a1.x, a1.y, a1.z, a1.w};
        v8bf ah, al;
        #pragma unroll
        for (int i = 0; i < 8; ++i) {
            const __bf16 h = (__bf16)av[i];
            ah[i] = h;
            al[i] = (__bf16)(av[i] - (float)h);
        }
        const int wo = l16 * 64 + ((quad ^ (l16 & 3)) << 4);
        #pragma unroll
        for (int j = 0; j < 3; ++j) {
            const char* base = wb + (cg * 3 + j) * 2048 + wo;
            const v8bf bh = *(const v8bf*)(base);
            const v8bf bl = *(const v8bf*)(base + 1024);
            acc[j] = MFMA_BF(ah, bh, acc[j]);
            acc[j] = MFMA_BF(ah, bl, acc[j]);
            acc[j] = MFMA_BF(al, bh, acc[j]);
        }
    };

    STAGE(0);
    STAGE(1);
    for (int ks = 0; ks < 31; ++ks) {
        SYNC_VM(WAIT_VM5);          // stage ks landed; stage ks+1 in flight
        if (ks + 2 < 32) STAGE(ks + 2);
        compute(ks);
    }
    SYNC_VM(WAIT_VM0);              // last stage fully landed
    compute(31);
    #undef STAGE

    // epilogue: C layout col=l16 (within ct), row=quad*4+reg
    #pragma unroll
    for (int j = 0; j < 3; ++j) {
        const int n = n0 + (cg * 3 + j) * 16 + l16;
        const float bias = (n < 64) ? bq[n] : ((n < 128) ? bk[n - 64] : bv[n - 128]);
        #pragma unroll
        for (int reg = 0; reg < 4; ++reg) {
            const int row = m0 + mt * 16 + quad * 4 + reg;
            const float v = acc[j][reg] + bias;
            if (n < 64) {
                const float s = v * QSC;             // fold 8*log2e into q
                const __bf16 hh = (__bf16)s;
                qh[(size_t)row * HS + n] = hh;
                ql[(size_t)row * HS + n] = (__bf16)(s - (float)hh);
            } else if (n < 128) {
                const __bf16 hh = (__bf16)v;
                kh[(size_t)row * HS + n - 64] = hh;
                kl[(size_t)row * HS + n - 64] = (__bf16)(v - (float)hh);
            } else {
                const int b2 = row >> 11, tt = row & 2047, hc = n - 128;
                vt[((size_t)(b2 * HS + hc)) * TT + tt] = (_Float16)v;
            }
        }
    }
}

// ---------------------------------------------------------------------------
// Flash attention (unchanged from round 9 — verified, best so far).
// Split-precision bf16 QK + fp16 PV, balanced pair grid (33 chunks/block),
// 256 blocks x 512 threads, per-wave dual (m,o,l) state, exp2 softmax,
// ones-column row sums, 2-stage LDS merge.
// ---------------------------------------------------------------------------
__global__ __launch_bounds__(512, 2) void attn(
    const __bf16* __restrict__ qh, const __bf16* __restrict__ ql,
    const __bf16* __restrict__ kh, const __bf16* __restrict__ kl,
    const _Float16* __restrict__ vt, float* __restrict__ out)
{
    __shared__ __align__(16) char smem_raw[69632];
    _Float16* ps = (_Float16*)smem_raw;
    float*    os = (float*)smem_raw;
    __shared__ float sm[8][2][16], sl[8][2][16];

    const int tid = threadIdx.x, lane = tid & 63, w = tid >> 6;
    const int quad = lane >> 4, l16 = lane & 15;
    const int b = blockIdx.x & 3, pair = blockIdx.x >> 2;   // pair 0..63
    const int q0t[2] = {(127 - pair) * 16, pair * 16};
    const int ntk0 = (q0t[0] + 16 + 63) >> 6;
    const int ntk1 = (q0t[1] + 16 + 63) >> 6;
    const int total = ntk0 + ntk1;                          // == 33

    v8bf Qh0[2], Qh1[2], Ql0[2], Ql1[2];
    #pragma unroll
    for (int t = 0; t < 2; ++t) {
        const size_t qrow = ((size_t)b * TT + q0t[t] + l16) * HS;
        Qh0[t] = *(const v8bf*)(qh + qrow + quad * 8);
        Qh1[t] = *(const v8bf*)(qh + qrow + 32 + quad * 8);
        Ql0[t] = *(const v8bf*)(ql + qrow + quad * 8);
        Ql1[t] = *(const v8bf*)(ql + qrow + 32 + quad * 8);
    }

    const v8h vones = {(_Float16)1.f, (_Float16)1.f, (_Float16)1.f, (_Float16)1.f,
                       (_Float16)1.f, (_Float16)1.f, (_Float16)1.f, (_Float16)1.f};

    float mr0[4] = {-3e38f, -3e38f, -3e38f, -3e38f};
    float mr1[4] = {-3e38f, -3e38f, -3e38f, -3e38f};
    v4f o0[4], o1[4], l40, l41;
    #pragma unroll
    for (int i = 0; i < 4; ++i) {
        o0[i] = (v4f){0.f, 0.f, 0.f, 0.f};
        o1[i] = (v4f){0.f, 0.f, 0.f, 0.f};
    }
    l40 = (v4f){0.f, 0.f, 0.f, 0.f};
    l41 = (v4f){0.f, 0.f, 0.f, 0.f};

    _Float16* pw = ps + w * (16 * 72);

    auto doChunk = [&](int j0, int q0c, int t,
                       float (&mrow)[4], v4f (&o)[4], v4f &o4) {
        v8bf Kh[8], Kl[8];
        v8h  Vf[8];
        #pragma unroll
        for (int nt = 0; nt < 4; ++nt) {
            const size_t krow = ((size_t)b * TT + j0 + nt * 16 + l16) * HS;
            Kh[nt * 2]     = *(const v8bf*)(kh + krow + quad * 8);
            Kh[nt * 2 + 1] = *(const v8bf*)(kh + krow + 32 + quad * 8);
            Kl[nt * 2]     = *(const v8bf*)(kl + krow + quad * 8);
            Kl[nt * 2 + 1] = *(const v8bf*)(kl + krow + 32 + quad * 8);
        }
        #pragma unroll
        for (int nt = 0; nt < 4; ++nt) {
            const size_t vrow = ((size_t)(b * HS + nt * 16 + l16)) * TT + j0;
            Vf[nt * 2]     = *(const v8h*)(vt + vrow + quad * 8);
            Vf[nt * 2 + 1] = *(const v8h*)(vt + vrow + 32 + quad * 8);
        }
        v4f s[4];
        #pragma unroll
        for (int i = 0; i < 4; ++i) s[i] = (v4f){0.f, 0.f, 0.f, 0.f};
        #pragma unroll
        for (int nt = 0; nt < 4; ++nt) {
            s[nt] = MFMA_BF(Qh0[t], Kh[nt * 2],     s[nt]);
            s[nt] = MFMA_BF(Qh1[t], Kh[nt * 2 + 1], s[nt]);
            s[nt] = MFMA_BF(Qh0[t], Kl[nt * 2],     s[nt]);
            s[nt] = MFMA_BF(Qh1[t], Kl[nt * 2 + 1], s[nt]);
            s[nt] = MFMA_BF(Ql0[t], Kh[nt * 2],     s[nt]);
            s[nt] = MFMA_BF(Ql1[t], Kh[nt * 2 + 1], s[nt]);
        }
        const int irow = q0c + quad * 4;
        float mx[4] = {-3e38f, -3e38f, -3e38f, -3e38f};
        #pragma unroll
        for (int nt = 0; nt < 4; ++nt)
            #pragma unroll
            for (int reg = 0; reg < 4; ++reg) {
                if (j0 + nt * 16 + l16 > irow + reg) s[nt][reg] = -3e38f;
                mx[reg] = fmaxf(mx[reg], s[nt][reg]);
            }
        #pragma unroll
        for (int off = 8; off; off >>= 1)
            #pragma unroll
            for (int reg = 0; reg < 4; ++reg)
                mx[reg] = fmaxf(mx[reg], __shfl_xor(mx[reg], off));
        float al[4];
        #pragma unroll
        for (int reg = 0; reg < 4; ++reg) {
            const float mn = fmaxf(mrow[reg], mx[reg]);
            al[reg] = exp2f(mrow[reg] - mn);
            mrow[reg] = mn;
        }
        #pragma unroll
        for (int nt = 0; nt < 4; ++nt)
            #pragma unroll
            for (int reg = 0; reg < 4; ++reg) {
                const float p = (j0 + nt * 16 + l16 > irow + reg)
                                    ? 0.f : exp2f(s[nt][reg] - mrow[reg]);
                pw[(quad * 4 + reg) * 72 + nt * 16 + l16] = (_Float16)p;
            }
        #pragma unroll
        for (int nt = 0; nt < 4; ++nt)
            #pragma unroll
            for (int reg = 0; reg < 4; ++reg)
                o[nt][reg] *= al[reg];
        #pragma unroll
        for (int reg = 0; reg < 4; ++reg)
            o4[reg] *= al[reg];
        const v8h Pa0 = *(const v8h*)(pw + l16 * 72 + quad * 8);
        const v8h Pa1 = *(const v8h*)(pw + l16 * 72 + 32 + quad * 8);
        #pragma unroll
        for (int nt = 0; nt < 4; ++nt) {
            o[nt] = MFMA_F16(Pa0, Vf[nt * 2],     o[nt]);
            o[nt] = MFMA_F16(Pa1, Vf[nt * 2 + 1], o[nt]);
        }
        o4 = MFMA_F16(Pa0, vones, o4);
        o4 = MFMA_F16(Pa1, vones, o4);
    };

    for (int c = w; c < total; c += 8) {
        if (c < ntk0) doChunk(c * 64,          q0t[0], 0, mr0, o0, l40);
        else          doChunk((c - ntk0) * 64, q0t[1], 1, mr1, o1, l41);
    }

    if (l16 == 0) {
        #pragma unroll
        for (int reg = 0; reg < 4; ++reg) {
            sm[w][0][quad * 4 + reg] = mr0[reg];
            sl[w][0][quad * 4 + reg] = l40[reg];
            sm[w][1][quad * 4 + reg] = mr1[reg];
            sl[w][1][quad * 4 + reg] = l41[reg];
        }
    }
    __syncthreads();

    #pragma unroll
    for (int t = 0; t < 2; ++t) {
        float sc[4];
        #pragma unroll
        for (int reg = 0; reg < 4; ++reg) {
            const int r = quad * 4 + reg;
            float M = sm[0][t][r];
            #pragma unroll
            for (int i = 1; i < 8; ++i) M = fmaxf(M, sm[i][t][r]);
            const float mw = t ? mr1[reg] : mr0[reg];
            sc[reg] = exp2f(mw - M);
        }
        float* ow = os + (size_t)(w * 2 + t) * (16 * 68);
        #pragma unroll
        for (int nt = 0; nt < 4; ++nt)
            #pragma unroll
            for (int reg = 0; reg < 4; ++reg) {
                const v4f& oo = t ? o1[nt] : o0[nt];
                ow[(quad * 4 + reg) * 68 + nt * 16 + l16] = oo[reg] * sc[reg];
            }
    }
    __syncthreads();

    #pragma unroll
    for (int kk = 0; kk < 4; ++kk) {
        const int g = w * 4 + kk;
        const int t = g >> 4, m = g & 15;
        float M = sm[0][t][m];
        #pragma unroll
        for (int i = 1; i < 8; ++i) M = fmaxf(M, sm[i][t][m]);
        float L = 0.f, val = 0.f;
        #pragma unroll
        for (int i = 0; i < 8; ++i) {
            L   += sl[i][t][m] * exp2f(sm[i][t][m] - M);
            val += os[(size_t)(i * 2 + t) * (16 * 68) + m * 68 + lane];
        }
        out[((size_t)b * TT + q0t[t] + m) * HS + lane] = val / L;
    }
}

// ---------------------------------------------------------------------------
extern "C" void kernel_launch(void* const* d_in, const int* in_sizes, int n_in,
                              void* d_out, int out_size, void* d_ws, size_t ws_size,
                              hipStream_t stream)
{
    const float* x  = (const float*)d_in[0];
    const float* Wq = (const float*)d_in[1];
    const float* bq = (const float*)d_in[2];
    const float* Wk = (const float*)d_in[3];
    const float* bk = (const float*)d_in[4];
    const float* Wv = (const float*)d_in[5];
    const float* bv = (const float*)d_in[6];
    float* out = (float*)d_out;

    const int rows = in_sizes[0] / NE;   // 8192
    char* p = (char*)d_ws;
    char* imgW = p;                           p += (size_t)32 * 24576;      // 768 KB
    __bf16* qhb = (__bf16*)p;                 p += (size_t)rows * HS * 2;
    __bf16* qlb = (__bf16*)p;                 p += (size_t)rows * HS * 2;
    __bf16* khb = (__bf16*)p;                 p += (size_t)rows * HS * 2;
    __bf16* klb = (__bf16*)p;                 p += (size_t)rows * HS * 2;
    _Float16* vtb = (_Float16*)p;             p += (size_t)rows * HS * 2;

    prep_w<<<dim3(16, 3), 256, 0, stream>>>(Wq, Wk, Wv, imgW);
    proj<<<dim3(rows / 64, 2), 512, 0, stream>>>(x, imgW, bq, bk, bv,
                                                 qhb, qlb, khb, klb, vtb);
    attn<<<rows / 32, 512, 0, stream>>>(qhb, qlb, khb, klb, vtb, out);
}

// Round 13
// 130.207 us; speedup vs baseline: 1.0521x; 1.0521x over previous
//
#include <hip/hip_runtime.h>
#include <math.h>

// B=4, T=2048, N_EMBD=1024, HEAD=64.
// Reference multiplies scores by sqrt(64)=8; we fold 8*log2(e) into q and use exp2.
#define NE 1024
#define HS 64
#define TT 2048
#define QSC 11.541560327111707f   // 8 * log2(e)

typedef __bf16    v8bf __attribute__((ext_vector_type(8)));
typedef _Float16  v8h  __attribute__((ext_vector_type(8)));
typedef float     v4f  __attribute__((ext_vector_type(4)));

#define MFMA_BF(a, b, c)  __builtin_amdgcn_mfma_f32_16x16x32_bf16((a), (b), (c), 0, 0, 0)
#define MFMA_F16(a, b, c) __builtin_amdgcn_mfma_f32_16x16x32_f16((a), (b), (c), 0, 0, 0)

// async global->LDS DMA (lands at wave-uniform base + lane*size)
__device__ __forceinline__ void gl_lds16(const void* g, void* l) {
    __builtin_amdgcn_global_load_lds(
        (const __attribute__((address_space(1))) unsigned int*)g,
        (__attribute__((address_space(3))) unsigned int*)l, 16, 0, 0);
}
__device__ __forceinline__ void gl_lds4(const void* g, void* l) {
    __builtin_amdgcn_global_load_lds(
        (const __attribute__((address_space(1))) unsigned int*)g,
        (__attribute__((address_space(3))) unsigned int*)l, 4, 0, 0);
}

// raw barrier with manual vmcnt: NO compiler-inserted vmcnt(0) drain.
// imm encoding (gfx9): vmcnt[3:0] | exp[6:4] | lgkm[11:8] | vmcnt[5:4]@[15:14]
#define SYNC_VM(imm) do {                                   \
    __asm__ __volatile__("" ::: "memory");                  \
    __builtin_amdgcn_s_waitcnt(imm);                        \
    __builtin_amdgcn_s_barrier();                           \
    __asm__ __volatile__("" ::: "memory");                  \
} while (0)
#define WAIT_VM8  0x0F78   // vmcnt(8): leave newest stage (8 DMAs) in flight
#define WAIT_VM0  0x0F70   // vmcnt(0)

// ---------------------------------------------------------------------------
// prep_w: build the W "image" — hi/lo bf16, pre-arranged so that a linear
// global_load_lds stream lands B-fragments in LDS with an XOR-16B swizzle.
// Image layout (bytes): [step 0..31][ct 0..11][plane hi/lo][c 0..15][p16 0..3][16B]
//   content of (step,ct,pl,c,p16) = W[k = step*32 + (p16^(c&3))*8 + j][n = ct*16+c]
// ---------------------------------------------------------------------------
__global__ __launch_bounds__(256) void prep_w(
    const float* __restrict__ Wq, const float* __restrict__ Wk,
    const float* __restrict__ Wv, char* __restrict__ imgW)
{
    __shared__ float t[64][65];
    const int bx = blockIdx.x, by = blockIdx.y;
    const float* W = (by == 0) ? Wq : ((by == 1) ? Wk : Wv);
    const int tid = threadIdx.x;
    const int cc = tid & 63, r4 = tid >> 6;
    #pragma unroll
    for (int p = 0; p < 16; ++p) {
        const int k = p * 4 + r4;
        t[k][cc] = W[(size_t)(bx * 64 + k) * HS + cc];   // coalesced
    }
    __syncthreads();
    #pragma unroll
    for (int e = 0; e < 4; ++e) {
        const int chunk = tid + e * 256;
        const int s2   = chunk >> 9;
        const int rem  = chunk & 511;
        const int ctl  = rem >> 7;
        const int rem2 = rem & 127;
        const int pl   = rem2 >> 6;
        const int rem3 = rem2 & 63;
        const int c    = rem3 >> 2;
        const int p16  = rem3 & 3;
        const int kb   = s2 * 32 + ((p16 ^ (c & 3)) << 3);
        const int ncol = ctl * 16 + c;
        v8bf o;
        #pragma unroll
        for (int j = 0; j < 8; ++j) {
            const float v = t[kb + j][ncol];
            const __bf16 h = (__bf16)v;
            o[j] = pl ? (__bf16)(v - (float)h) : h;
        }
        *(v8bf*)(imgW + (size_t)(bx * 2 + s2) * 24576
                 + (by * 4 + ctl) * 2048 + pl * 1024 + c * 64 + p16 * 16) = o;
    }
}

// ---------------------------------------------------------------------------
// Projection GEMM (round-11 structure, best measured): 512 blocks x 256 thr,
// block = 16 rows x 192 cols, full K, 2 blocks/CU, triple-buffered async-DMA
// staging with raw barrier + manual vmcnt (8 DMAs/thread/stage -> vmcnt(8)).
// Epilogue: q (x QSC) hi/lo fp16, k single fp16, v^T fp16.
// ---------------------------------------------------------------------------
__global__ __launch_bounds__(256, 2) void proj(
    const float* __restrict__ x, const char* __restrict__ imgW,
    const float* __restrict__ bq, const float* __restrict__ bk,
    const float* __restrict__ bv,
    _Float16* __restrict__ qh, _Float16* __restrict__ ql,
    _Float16* __restrict__ kf, _Float16* __restrict__ vt)
{
    __shared__ __align__(16) char sbuf[3][26624];   // [buf][x 2KB | W 24KB]

    const int tid = threadIdx.x, lane = tid & 63, cg = tid >> 6;
    const int quad = lane >> 4, l16 = lane & 15;
    const int m0 = blockIdx.x * 16;

    // x staging via two width-4 DMAs per lane: wave wv covers rows 4wv..4wv+3
    const int wv = cg;
    const int xr0 = wv * 4 + (lane >> 5);            // rows r0, r0+2
    const int xr1 = xr0 + 2;
    const int xp  = (lane >> 3) & 3;                 // 32B slot
    const int xj  = lane & 7;                        // element in chunk
    const float* gx0 = x + (size_t)(m0 + xr0) * NE + ((xp ^ (xr0 & 3)) << 3) + xj;
    const float* gx1 = x + (size_t)(m0 + xr1) * NE + ((xp ^ (xr1 & 3)) << 3) + xj;
    const int xl0 = wv * 512 + (lane & 63) * 4;      // lds byte offsets
    const int xl1 = xl0 + 256;
    const char* gw = imgW + (size_t)tid * 16;

    v4f acc[3];
    #pragma unroll
    for (int i = 0; i < 3; ++i) acc[i] = (v4f){0.f, 0.f, 0.f, 0.f};

    #define STAGE(ks, xb_)  do {                                          \
        gl_lds4(gx0 + (ks) * 32, (xb_) + xl0);                            \
        gl_lds4(gx1 + (ks) * 32, (xb_) + xl1);                            \
        const char* gws_ = gw + (size_t)(ks) * 24576;                     \
        _Pragma("unroll")                                                 \
        for (int j_ = 0; j_ < 6; ++j_)                                    \
            gl_lds16(gws_ + j_ * 4096, (xb_) + 2048 + tid * 16 + j_ * 4096); \
    } while (0)

    auto compute = [&](int ks) {
        const char* xb = sbuf[ks % 3];
        const char* wb = xb + 2048;
        const int rl = l16;
        const int pA = quad ^ (rl & 3);
        const float4 a0 = *(const float4*)(xb + rl * 128 + pA * 32);
        const float4 a1 = *(const float4*)(xb + rl * 128 + pA * 32 + 16);
        const float av[8] = {a0.x, a0.y, a0.z, a0.w, a1.x, a1.y, a1.z, a1.w};
        v8bf ah, al;
        #pragma unroll
        for (int i = 0; i < 8; ++i) {
            const __bf16 h = (__bf16)av[i];
            ah[i] = h;
            al[i] = (__bf16)(av[i] - (float)h);
        }
        const int wo = l16 * 64 + ((quad ^ (l16 & 3)) << 4);
        #pragma unroll
        for (int j = 0; j < 3; ++j) {
            const char* base = wb + (cg * 3 + j) * 2048 + wo;
            const v8bf bh = *(const v8bf*)(base);
            const v8bf bl = *(const v8bf*)(base + 1024);
            acc[j] = MFMA_BF(ah, bh, acc[j]);
            acc[j] = MFMA_BF(ah, bl, acc[j]);
            acc[j] = MFMA_BF(al, bh, acc[j]);
        }
    };

    STAGE(0, sbuf[0]);
    STAGE(1, sbuf[1]);
    for (int ks = 0; ks < 31; ++ks) {
        SYNC_VM(WAIT_VM8);          // drains stage ks; stage ks+1 stays in flight
        if (ks + 2 < 32) STAGE(ks + 2, sbuf[(ks + 2) % 3]);
        compute(ks);
    }
    SYNC_VM(WAIT_VM0);              // last stage must be fully landed
    compute(31);
    #undef STAGE

    // epilogue: C layout col=l16 (within n-tile), row=quad*4+reg
    #pragma unroll
    for (int j = 0; j < 3; ++j) {
        const int n = cg * 48 + j * 16 + l16;
        const float bias = (n < 64) ? bq[n] : ((n < 128) ? bk[n - 64] : bv[n - 128]);
        #pragma unroll
        for (int reg = 0; reg < 4; ++reg) {
            const int row = m0 + quad * 4 + reg;
            const float v = acc[j][reg] + bias;
            if (n < 64) {
                const float s = v * QSC;             // fold 8*log2e into q
                const _Float16 hh = (_Float16)s;
                qh[(size_t)row * HS + n] = hh;
                ql[(size_t)row * HS + n] = (_Float16)(s - (float)hh);
            } else if (n < 128) {
                kf[(size_t)row * HS + n - 64] = (_Float16)v;
            } else {
                const int b2 = row >> 11, tt = row & 2047, hc = n - 128;
                vt[((size_t)(b2 * HS + hc)) * TT + tt] = (_Float16)v;
            }
        }
    }
}

// ---------------------------------------------------------------------------
// Flash attention: fp16 hi/lo Q x fp16 single K (2-product QK, 16 MFMA/chunk,
// half the K bytes of bf16 hi/lo), fp16 PV. Balanced pair grid (33 chunks per
// block), 256 blocks x 512 threads, per-wave dual (m,o,l) state, exp2
// softmax, ones-column row sums, 2-stage LDS merge.
// ---------------------------------------------------------------------------
__global__ __launch_bounds__(512, 2) void attn(
    const _Float16* __restrict__ qh, const _Float16* __restrict__ ql,
    const _Float16* __restrict__ kf, const _Float16* __restrict__ vt,
    float* __restrict__ out)
{
    __shared__ __align__(16) char smem_raw[69632];
    _Float16* ps = (_Float16*)smem_raw;
    float*    os = (float*)smem_raw;
    __shared__ float sm[8][2][16], sl[8][2][16];

    const int tid = threadIdx.x, lane = tid & 63, w = tid >> 6;
    const int quad = lane >> 4, l16 = lane & 15;
    const int b = blockIdx.x & 3, pair = blockIdx.x >> 2;   // pair 0..63
    const int q0t[2] = {(127 - pair) * 16, pair * 16};
    const int ntk0 = (q0t[0] + 16 + 63) >> 6;
    const int ntk1 = (q0t[1] + 16 + 63) >> 6;
    const int total = ntk0 + ntk1;                          // == 33

    v8h Qh0[2], Qh1[2], Ql0[2], Ql1[2];
    #pragma unroll
    for (int t = 0; t < 2; ++t) {
        const size_t qrow = ((size_t)b * TT + q0t[t] + l16) * HS;
        Qh0[t] = *(const v8h*)(qh + qrow + quad * 8);
        Qh1[t] = *(const v8h*)(qh + qrow + 32 + quad * 8);
        Ql0[t] = *(const v8h*)(ql + qrow + quad * 8);
        Ql1[t] = *(const v8h*)(ql + qrow + 32 + quad * 8);
    }

    const v8h vones = {(_Float16)1.f, (_Float16)1.f, (_Float16)1.f, (_Float16)1.f,
                       (_Float16)1.f, (_Float16)1.f, (_Float16)1.f, (_Float16)1.f};

    float mr0[4] = {-3e38f, -3e38f, -3e38f, -3e38f};
    float mr1[4] = {-3e38f, -3e38f, -3e38f, -3e38f};
    v4f o0[4], o1[4], l40, l41;
    #pragma unroll
    for (int i = 0; i < 4; ++i) {
        o0[i] = (v4f){0.f, 0.f, 0.f, 0.f};
        o1[i] = (v4f){0.f, 0.f, 0.f, 0.f};
    }
    l40 = (v4f){0.f, 0.f, 0.f, 0.f};
    l41 = (v4f){0.f, 0.f, 0.f, 0.f};

    _Float16* pw = ps + w * (16 * 72);

    auto doChunk = [&](int j0, int q0c, int t,
                       float (&mrow)[4], v4f (&o)[4], v4f &o4) {
        v8h Kf[8], Vf[8];
        #pragma unroll
        for (int nt = 0; nt < 4; ++nt) {
            const size_t krow = ((size_t)b * TT + j0 + nt * 16 + l16) * HS;
            Kf[nt * 2]     = *(const v8h*)(kf + krow + quad * 8);
            Kf[nt * 2 + 1] = *(const v8h*)(kf + krow + 32 + quad * 8);
        }
        #pragma unroll
        for (int nt = 0; nt < 4; ++nt) {
            const size_t vrow = ((size_t)(b * HS + nt * 16 + l16)) * TT + j0;
            Vf[nt * 2]     = *(const v8h*)(vt + vrow + quad * 8);
            Vf[nt * 2 + 1] = *(const v8h*)(vt + vrow + 32 + quad * 8);
        }
        v4f s[4];
        #pragma unroll
        for (int i = 0; i < 4; ++i) s[i] = (v4f){0.f, 0.f, 0.f, 0.f};
        #pragma unroll
        for (int nt = 0; nt < 4; ++nt) {
            s[nt] = MFMA_F16(Qh0[t], Kf[nt * 2],     s[nt]);
            s[nt] = MFMA_F16(Qh1[t], Kf[nt * 2 + 1], s[nt]);
            s[nt] = MFMA_F16(Ql0[t], Kf[nt * 2],     s[nt]);
            s[nt] = MFMA_F16(Ql1[t], Kf[nt * 2 + 1], s[nt]);
        }
        const int irow = q0c + quad * 4;
        float mx[4] = {-3e38f, -3e38f, -3e38f, -3e38f};
        #pragma unroll
        for (int nt = 0; nt < 4; ++nt)
            #pragma unroll
            for (int reg = 0; reg < 4; ++reg) {
                if (j0 + nt * 16 + l16 > irow + reg) s[nt][reg] = -3e38f;
                mx[reg] = fmaxf(mx[reg], s[nt][reg]);
            }
        #pragma unroll
        for (int off = 8; off; off >>= 1)
            #pragma unroll
            for (int reg = 0; reg < 4; ++reg)
                mx[reg] = fmaxf(mx[reg], __shfl_xor(mx[reg], off));
        float al[4];
        #pragma unroll
        for (int reg = 0; reg < 4; ++reg) {
            const float mn = fmaxf(mrow[reg], mx[reg]);
            al[reg] = exp2f(mrow[reg] - mn);
            mrow[reg] = mn;
        }
        #pragma unroll
        for (int nt = 0; nt < 4; ++nt)
            #pragma unroll
            for (int reg = 0; reg < 4; ++reg) {
                const float p = (j0 + nt * 16 + l16 > irow + reg)
                                    ? 0.f : exp2f(s[nt][reg] - mrow[reg]);
                pw[(quad * 4 + reg) * 72 + nt * 16 + l16] = (_Float16)p;
            }
        #pragma unroll
        for (int nt = 0; nt < 4; ++nt)
            #pragma unroll
            for (int reg = 0; reg < 4; ++reg)
                o[nt][reg] *= al[reg];
        #pragma unroll
        for (int reg = 0; reg < 4; ++reg)
            o4[reg] *= al[reg];
        const v8h Pa0 = *(const v8h*)(pw + l16 * 72 + quad * 8);
        const v8h Pa1 = *(const v8h*)(pw + l16 * 72 + 32 + quad * 8);
        #pragma unroll
        for (int nt = 0; nt < 4; ++nt) {
            o[nt] = MFMA_F16(Pa0, Vf[nt * 2],     o[nt]);
            o[nt] = MFMA_F16(Pa1, Vf[nt * 2 + 1], o[nt]);
        }
        o4 = MFMA_F16(Pa0, vones, o4);
        o4 = MFMA_F16(Pa1, vones, o4);
    };

    for (int c = w; c < total; c += 8) {
        if (c < ntk0) doChunk(c * 64,          q0t[0], 0, mr0, o0, l40);
        else          doChunk((c - ntk0) * 64, q0t[1], 1, mr1, o1, l41);
    }

    if (l16 == 0) {
        #pragma unroll
        for (int reg = 0; reg < 4; ++reg) {
            sm[w][0][quad * 4 + reg] = mr0[reg];
            sl[w][0][quad * 4 + reg] = l40[reg];
            sm[w][1][quad * 4 + reg] = mr1[reg];
            sl[w][1][quad * 4 + reg] = l41[reg];
        }
    }
    __syncthreads();

    #pragma unroll
    for (int t = 0; t < 2; ++t) {
        float sc[4];
        #pragma unroll
        for (int reg = 0; reg < 4; ++reg) {
            const int r = quad * 4 + reg;
            float M = sm[0][t][r];
            #pragma unroll
            for (int i = 1; i < 8; ++i) M = fmaxf(M, sm[i][t][r]);
            const float mw = t ? mr1[reg] : mr0[reg];
            sc[reg] = exp2f(mw - M);
        }
        float* ow = os + (size_t)(w * 2 + t) * (16 * 68);
        #pragma unroll
        for (int nt = 0; nt < 4; ++nt)
            #pragma unroll
            for (int reg = 0; reg < 4; ++reg) {
                const v4f& oo = t ? o1[nt] : o0[nt];
                ow[(quad * 4 + reg) * 68 + nt * 16 + l16] = oo[reg] * sc[reg];
            }
    }
    __syncthreads();

    #pragma unroll
    for (int kk = 0; kk < 4; ++kk) {
        const int g = w * 4 + kk;
        const int t = g >> 4, m = g & 15;
        float M = sm[0][t][m];
        #pragma unroll
        for (int i = 1; i < 8; ++i) M = fmaxf(M, sm[i][t][m]);
        float L = 0.f, val = 0.f;
        #pragma unroll
        for (int i = 0; i < 8; ++i) {
            L   += sl[i][t][m] * exp2f(sm[i][t][m] - M);
            val += os[(size_t)(i * 2 + t) * (16 * 68) + m * 68 + lane];
        }
        out[((size_t)b * TT + q0t[t] + m) * HS + lane] = val / L;
    }
}

// ---------------------------------------------------------------------------
extern "C" void kernel_launch(void* const* d_in, const int* in_sizes, int n_in,
                              void* d_out, int out_size, void* d_ws, size_t ws_size,
                              hipStream_t stream)
{
    const float* x  = (const float*)d_in[0];
    const float* Wq = (const float*)d_in[1];
    const float* bq = (const float*)d_in[2];
    const float* Wk = (const float*)d_in[3];
    const float* bk = (const float*)d_in[4];
    const float* Wv = (const float*)d_in[5];
    const float* bv = (const float*)d_in[6];
    float* out = (float*)d_out;

    const int rows = in_sizes[0] / NE;   // 8192
    char* p = (char*)d_ws;
    char* imgW = p;                           p += (size_t)32 * 24576;      // 768 KB
    _Float16* qhb = (_Float16*)p;             p += (size_t)rows * HS * 2;
    _Float16* qlb = (_Float16*)p;             p += (size_t)rows * HS * 2;
    _Float16* kfb = (_Float16*)p;             p += (size_t)rows * HS * 2;
    _Float16* vtb = (_Float16*)p;             p += (size_t)rows * HS * 2;

    prep_w<<<dim3(16, 3), 256, 0, stream>>>(Wq, Wk, Wv, imgW);
    proj<<<rows / 16, 256, 0, stream>>>(x, imgW, bq, bk, bv,
                                        qhb, qlb, kfb, vtb);
    attn<<<rows / 32, 512, 0, stream>>>(qhb, qlb, kfb, vtb, out);
}